// Round 6
// baseline (682.705 us; speedup 1.0000x reference)
//
#include <hip/hip_runtime.h>
#include <math.h>

#define SCOPE_AGENT __HIP_MEMORY_SCOPE_AGENT
typedef unsigned long long u64;
typedef unsigned int u32;

__device__ __forceinline__ float dot4_(float4 a, float4 b) {
    return a.x * b.x + a.y * b.y + a.z * b.z + a.w * b.w;
}
__device__ __forceinline__ u64 pack_(float v, int tag) {
    return ((u64)(u32)tag << 32) | (u64)__float_as_uint(v);
}
// fast transcendentals (tolerance 1.07e-2; measured absmax 4.9e-4 in R5)
__device__ __forceinline__ float sigm_f(float x) {
    return __builtin_amdgcn_rcpf(1.f + __builtin_amdgcn_exp2f(-1.44269504f * x));
}
__device__ __forceinline__ float tanh_f(float x) {
    return 2.f * __builtin_amdgcn_rcpf(1.f + __builtin_amdgcn_exp2f(-2.88539008f * x)) - 1.f;
}

// ---------------------------------------------------------------------------
// K1: 8 constant-input LSTM chains, 128 steps. 256 blocks = 8 dirs x 32 WGs,
// 512 threads (8 waves). LLC-only tagged exchange (R3-proven; R4/R5 showed
// placement-dependent fast paths regress). NEW vs R3: wave w owns BOTH
// complete units {wg*16+2w, +1} — all 4 gates intra-wave — so the produce
// path is dots -> 3x shfl_xor -> parallel activations (all lanes, fast exp)
// -> 4x shfl -> immediate store. No barrier, no LDS between dot and publish;
// exactly ONE __syncthreads per step (after consume).
// ---------------------------------------------------------------------------
extern "C" __global__ __launch_bounds__(512, 1)
void lstm_k(const float* __restrict__ qWhh, const float* __restrict__ qbih,
            const float* __restrict__ qbhh, const float* __restrict__ eWhh,
            const float* __restrict__ ebih, const float* __restrict__ ebhh,
            u64* __restrict__ llcb)
{
    const int b  = blockIdx.x;
    const int d  = b >> 5;     // direction 0..7
    const int wg = b & 31;     // WG within direction
    const int t  = threadIdx.x;
    const int wv = t >> 6;     // wave 0..7
    const int l  = t & 63;     // lane
    const int usel = l >> 5;          // which of the wave's 2 units
    const int li   = l & 31;          // lane within unit
    const int gate = li >> 3;         // 0..3 (i,f,g,o)
    const int cc   = l & 7;           // column chunk (64 cols)
    const int gu   = wg * 16 + wv * 2 + usel;   // global unit 0..511
    const int wrow = gate * 512 + gu;           // row of Whh [2048 x 512]

    const float *Whh, *bih, *bhh;
    if (d < 2) {
        Whh = qWhh + (size_t)d * 2048 * 512;
        bih = qbih + d * 2048;
        bhh = qbhh + d * 2048;
    } else {
        Whh = eWhh + (size_t)(d - 2) * 2048 * 512;
        bih = ebih + (d - 2) * 2048;
        bhh = ebhh + (d - 2) * 2048;
    }

    // 64 weight floats/lane, pinned resident
    float4 w4[16];
    {
        const float4* wr = (const float4*)(Whh + (size_t)wrow * 512 + cc * 64);
        #pragma unroll
        for (int k = 0; k < 16; k++) w4[k] = wr[k];
    }
    #pragma unroll
    for (int k = 0; k < 16; k++)
        asm volatile("" : "+v"(w4[k].x), "+v"(w4[k].y), "+v"(w4[k].z), "+v"(w4[k].w));

    // per-lane: preactivation bias for (gate, gu); cell state replicated
    // across the unit's 32 lanes (identical updates, no gather needed)
    const float pre_l = bih[gate * 512 + gu] + bhh[gate * 512 + gu];
    float c = 0.f;

    // h staged in LDS: 8 chunks of 64 padded to 68 (R3-proven conflict-free)
    __shared__ __align__(16) float h_pad[8 * 68];
    for (int j = t; j < 8 * 68; j += 512) h_pad[j] = 0.f;
    __syncthreads();

    u64* llc0 = llcb + d * 512;

    for (int step = 1; step <= 128; step++) {
        // my row's partial dot over my 64 columns
        const float4* hv = (const float4*)(h_pad + cc * 68);
        float s = 0.f;
        #pragma unroll
        for (int k = 0; k < 16; k++) s += dot4_(w4[k], hv[k]);
        // reduce over the 8-lane column group -> every lane has (unit,gate) sum
        s += __shfl_xor(s, 1, 64);
        s += __shfl_xor(s, 2, 64);
        s += __shfl_xor(s, 4, 64);

        // parallel activations in ALL lanes (redundant x8 per gate — free)
        float x = pre_l + s;
        float act = (gate == 2) ? tanh_f(x) : sigm_f(x);
        // gather my unit's 4 activated gates (intra-wave, no LDS/barrier)
        const int ub = l & 32;
        float ii = __shfl(act, ub + 0, 64);
        float ff = __shfl(act, ub + 8, 64);
        float gg = __shfl(act, ub + 16, 64);
        float oo = __shfl(act, ub + 24, 64);
        c = ff * c + ii * gg;
        float hh = oo * tanh_f(c);

        u64* llcp = llc0 + (step & 1) * 4096;
        if (li == 0)   // one lane per unit publishes immediately
            __hip_atomic_store(&llcp[gu], pack_(hh, step),
                               __ATOMIC_RELAXED, SCOPE_AGENT);

        // consume: thread t polls unit t's tagged word (pipelined 3-load)
        u64 w;
        for (;;) {
            u64 a0 = __hip_atomic_load(&llcp[t], __ATOMIC_RELAXED, SCOPE_AGENT);
            u64 a1 = __hip_atomic_load(&llcp[t], __ATOMIC_RELAXED, SCOPE_AGENT);
            u64 a2 = __hip_atomic_load(&llcp[t], __ATOMIC_RELAXED, SCOPE_AGENT);
            if ((int)(a0 >> 32) == step) { w = a0; break; }
            if ((int)(a1 >> 32) == step) { w = a1; break; }
            if ((int)(a2 >> 32) == step) { w = a2; break; }
        }
        h_pad[(t >> 6) * 68 + (t & 63)] = __uint_as_float((u32)w);
        __syncthreads();   // the ONLY barrier per step
    }
    // final h (step 128, parity 0) is in llcb plane 0
}

// ---------------------------------------------------------------------------
// K2: fused gi + 3x(gh+upd) + ans1. 64 blocks x 512 threads (R3-proven).
// ---------------------------------------------------------------------------
extern "C" __global__ __launch_bounds__(512, 1)
void mid_k(const float* __restrict__ gWih, const float* __restrict__ gWhh,
           const float* __restrict__ gbih, const float* __restrict__ gbhh,
           const float* __restrict__ aW1, const float* __restrict__ ab1,
           const u64* __restrict__ hbuf, u64* __restrict__ mem2,
           float* __restrict__ avec)
{
    const int b = blockIdx.x;
    const int t = threadIdx.x;
    const int wave = t >> 6, lane = t & 63;

    __shared__ __align__(16) float rst[3072];
    __shared__ __align__(16) float meml[1024];
    __shared__ float gil[144];
    __shared__ float ghl[48];

    for (int i = t; i < 3072; i += 512)
        rst[i] = __uint_as_float((u32)hbuf[1024 + i]);
    __syncthreads();

    for (int r = wave; r < 144; r += 8) {
        int hop = r / 48, rr = r % 48;
        int g3 = rr >> 4, jj = rr & 15;
        int grow_g = g3 * 1024 + b * 16 + jj;
        const float* wp = gWih + (size_t)grow_g * 1024;
        const float* rp = rst + hop * 1024;
        float acc = 0.f;
        #pragma unroll
        for (int cch = 0; cch < 4; cch++) {
            float4 wv = *(const float4*)(wp + cch * 256 + lane * 4);
            float4 xv = *(const float4*)(rp + cch * 256 + lane * 4);
            acc += dot4_(wv, xv);
        }
        #pragma unroll
        for (int o = 32; o > 0; o >>= 1) acc += __shfl_xor(acc, o, 64);
        if (lane == 0) gil[r] = acc + gbih[grow_g];
    }

    for (int h = 0; h < 3; h++) {
        __syncthreads();
        if (h == 0) {
            for (int i = t; i < 1024; i += 512)
                meml[i] = __uint_as_float((u32)hbuf[i]);
        } else {
            const u64* mp = mem2 + (size_t)((h - 1) & 1) * 1024;
            for (int i = t; i < 1024; i += 512) {
                u64 w;
                for (;;) {
                    w = __hip_atomic_load(&mp[i], __ATOMIC_RELAXED, SCOPE_AGENT);
                    if ((int)(w >> 32) == h) break;
                    __builtin_amdgcn_s_sleep(1);
                }
                meml[i] = __uint_as_float((u32)w);
            }
        }
        __syncthreads();
        for (int r = wave; r < 48; r += 8) {
            int g3 = r >> 4, jj = r & 15;
            int grow_g = g3 * 1024 + b * 16 + jj;
            const float* wp = gWhh + (size_t)grow_g * 1024;
            float acc = 0.f;
            #pragma unroll
            for (int cch = 0; cch < 4; cch++) {
                float4 wv = *(const float4*)(wp + cch * 256 + lane * 4);
                float4 xv = *(const float4*)(meml + cch * 256 + lane * 4);
                acc += dot4_(wv, xv);
            }
            #pragma unroll
            for (int o = 32; o > 0; o >>= 1) acc += __shfl_xor(acc, o, 64);
            if (lane == 0) ghl[r] = acc + gbhh[grow_g];
        }
        __syncthreads();
        if (t < 16) {
            int j = b * 16 + t;
            float rr_ = sigm_f(gil[h * 48 + t]      + ghl[t]);
            float zz  = sigm_f(gil[h * 48 + 16 + t] + ghl[16 + t]);
            float nn  = tanh_f(gil[h * 48 + 32 + t] + rr_ * ghl[32 + t]);
            float mnew = (1.f - zz) * nn + zz * meml[j];
            __hip_atomic_store(&mem2[(size_t)(h & 1) * 1024 + j], pack_(mnew, h + 1),
                               __ATOMIC_RELAXED, SCOPE_AGENT);
        }
    }
    __syncthreads();
    for (int i = t; i < 1024; i += 512) {
        u64 w;
        for (;;) {
            w = __hip_atomic_load(&mem2[i], __ATOMIC_RELAXED, SCOPE_AGENT);
            if ((int)(w >> 32) == 3) break;
            __builtin_amdgcn_s_sleep(1);
        }
        meml[i] = __uint_as_float((u32)w);
    }
    __syncthreads();
    {
        int row = b * 8 + wave;
        const float* wp = aW1 + (size_t)row * 1024;
        float acc = 0.f;
        #pragma unroll
        for (int cch = 0; cch < 4; cch++) {
            float4 wv = *(const float4*)(wp + cch * 256 + lane * 4);
            float4 xv = *(const float4*)(meml + cch * 256 + lane * 4);
            acc += dot4_(wv, xv);
        }
        #pragma unroll
        for (int o = 32; o > 0; o >>= 1) acc += __shfl_xor(acc, o, 64);
        if (lane == 0) avec[row] = fmaxf(acc + ab1[row], 0.f);
    }
}

// ---------------------------------------------------------------------------
// K3: logits (32000 rows) + three uniform attention outputs (exactly 1/256).
// ---------------------------------------------------------------------------
extern "C" __global__ void ans2_k(const float* __restrict__ W2, const float* __restrict__ b2,
                                  const float* __restrict__ avec, float* __restrict__ out)
{
    const int t = threadIdx.x;
    if (blockIdx.x == 0) {
        out[t]       = 1.0f / 256.0f;
        out[t + 256] = 1.0f / 256.0f;
        out[t + 512] = 1.0f / 256.0f;
    }
    const int waveId = (blockIdx.x * 256 + t) >> 6;
    const int lane = t & 63;
    const int nw = gridDim.x * 4;
    const float4* av = (const float4*)(avec + lane * 8);
    float4 a0 = av[0], a1 = av[1];
    for (int row = waveId; row < 32000; row += nw) {
        const float4* wr = (const float4*)(W2 + (size_t)row * 512 + lane * 8);
        float acc = dot4_(wr[0], a0) + dot4_(wr[1], a1);
        #pragma unroll
        for (int o = 32; o > 0; o >>= 1) acc += __shfl_xor(acc, o, 64);
        if (lane == 0) out[768 + row] = acc + b2[row];
    }
}

// ---------------------------------------------------------------------------
extern "C" void kernel_launch(void* const* d_in, const int* in_sizes, int n_in,
                              void* d_out, int out_size, void* d_ws, size_t ws_size,
                              hipStream_t stream)
{
    (void)in_sizes; (void)n_in; (void)out_size; (void)ws_size;
    const float* qWhh = (const float*)d_in[1];
    const float* qbih = (const float*)d_in[2];
    const float* qbhh = (const float*)d_in[3];
    const float* eWhh = (const float*)d_in[5];
    const float* ebih = (const float*)d_in[6];
    const float* ebhh = (const float*)d_in[7];
    const float* gWih = (const float*)d_in[10];
    const float* gWhh = (const float*)d_in[11];
    const float* gbih = (const float*)d_in[12];
    const float* gbhh = (const float*)d_in[13];
    const float* aW1  = (const float*)d_in[14];
    const float* ab1  = (const float*)d_in[15];
    const float* aW2  = (const float*)d_in[16];
    const float* ab2  = (const float*)d_in[17];
    float* out = (float*)d_out;

    char* ws = (char*)d_ws;
    u64*   llcb = (u64*)ws;                    // 2 parity x 8 dir x 512 x 8B = 64 KB
    u64*   mem2 = (u64*)(ws + 65536);          // 2 parity x 1024 x 8B = 16 KB
    float* avec = (float*)(ws + 81920);        // 512 fp32 = 2 KB

    // No memset: 0xAA poison tag never equals a valid step/hop tag.

    hipLaunchKernelGGL(lstm_k, dim3(256), dim3(512), 0, stream,
                       qWhh, qbih, qbhh, eWhh, ebih, ebhh, llcb);
    hipLaunchKernelGGL(mid_k, dim3(64), dim3(512), 0, stream,
                       gWih, gWhh, gbih, gbhh, aW1, ab1, llcb, mem2, avec);
    hipLaunchKernelGGL(ans2_k, dim3(512), dim3(256), 0, stream, aW2, ab2, avec, out);
}

// Round 7
// 521.878 us; speedup vs baseline: 1.3082x; 1.3082x over previous
//
#include <hip/hip_runtime.h>
#include <math.h>

#define SCOPE_AGENT __HIP_MEMORY_SCOPE_AGENT
typedef unsigned long long u64;
typedef unsigned int u32;

__device__ __forceinline__ float dot4_(float4 a, float4 b) {
    return a.x * b.x + a.y * b.y + a.z * b.z + a.w * b.w;
}
__device__ __forceinline__ u64 pack_(float v, int tag) {
    return ((u64)(u32)tag << 32) | (u64)__float_as_uint(v);
}
// fast transcendentals (tolerance 1.07e-2; measured absmax 4.9e-4 in R5/R6)
__device__ __forceinline__ float sigm_f(float x) {
    return __builtin_amdgcn_rcpf(1.f + __builtin_amdgcn_exp2f(-1.44269504f * x));
}
__device__ __forceinline__ float tanh_f(float x) {
    return 2.f * __builtin_amdgcn_rcpf(1.f + __builtin_amdgcn_exp2f(-2.88539008f * x)) - 1.f;
}

// ---------------------------------------------------------------------------
// K1: 8 constant-input LSTM chains, 128 steps. 256 blocks = 8 dirs x 32 WGs,
// 512 threads. R3-proven skeleton (best measured: 1.92us/step) with two
// targeted fixes from the R6 post-mortem:
//  * PUBLISH stays wave-0-coalesced: t<16 contiguous lanes store 16x8B =
//    1-2 x 128B transactions/block/step. (R6's 8-wave scattered publish
//    doubled WRITE_SIZE via partial-line RMWs and regressed 2x.)
//  * CONSUME: ONE polling wave per block (wave 1). Each lane polls its 8
//    units with 8 pipelined 8B tagged loads -> 8x less chip-wide poll
//    traffic on the 64 hot LLC lines, one-RT discovery, stages into LDS.
//  * Activations: parallel across wave 0's 64 lanes w/ fast v_exp_f32,
//    shfl-gathered to t<16 (replaces R3's 5 serialized libm calls).
// Tag+parity protocol unchanged (max-skew-1 proof holds; poison 0xAA tag
// is negative, never matches step 1..128 -> no init needed).
// ---------------------------------------------------------------------------
extern "C" __global__ __launch_bounds__(512, 1)
void lstm_k(const float* __restrict__ qWhh, const float* __restrict__ qbih,
            const float* __restrict__ qbhh, const float* __restrict__ eWhh,
            const float* __restrict__ ebih, const float* __restrict__ ebhh,
            u64* __restrict__ llcb)
{
    const int b  = blockIdx.x;
    const int d  = b >> 5;     // direction 0..7
    const int wg = b & 31;     // WG within direction
    const int t  = threadIdx.x;
    const int rl = t >> 3;     // local row 0..63
    const int cc = t & 7;      // column chunk (64 cols)
    const int gate = rl >> 4;  // i,f,g,o
    const int ul   = rl & 15;
    const int gu   = wg * 16 + ul;        // global unit 0..511
    const int wrow = gate * 512 + gu;     // row of Whh [2048 x 512]

    const float *Whh, *bih, *bhh;
    if (d < 2) {
        Whh = qWhh + (size_t)d * 2048 * 512;
        bih = qbih + d * 2048;
        bhh = qbhh + d * 2048;
    } else {
        Whh = eWhh + (size_t)(d - 2) * 2048 * 512;
        bih = ebih + (d - 2) * 2048;
        bhh = ebhh + (d - 2) * 2048;
    }

    // 64 weight floats/lane, pinned
    float4 w4[16];
    {
        const float4* wr = (const float4*)(Whh + (size_t)wrow * 512 + cc * 64);
        #pragma unroll
        for (int k = 0; k < 16; k++) w4[k] = wr[k];
    }
    #pragma unroll
    for (int k = 0; k < 16; k++)
        asm volatile("" : "+v"(w4[k].x), "+v"(w4[k].y), "+v"(w4[k].z), "+v"(w4[k].w));

    // wave 0 lane t<64 owns (gate lg = t>>4, unit lu = t&15) for activations
    const int lg = t >> 4;
    const int lu = t & 15;
    float pre_l = 0.f, c = 0.f;
    if (t < 64) pre_l = bih[lg * 512 + wg * 16 + lu] + bhh[lg * 512 + wg * 16 + lu];

    __shared__ __align__(16) float h_pad[8 * 68];
    __shared__ float grow[64];
    for (int j = t; j < 8 * 68; j += 512) h_pad[j] = 0.f;
    __syncthreads();

    u64* llc0 = llcb + d * 512;

    for (int step = 1; step <= 128; step++) {
        // all waves: partial dot (my row, my 64 cols)
        const float4* hv = (const float4*)(h_pad + cc * 68);
        float s = 0.f;
        #pragma unroll
        for (int k = 0; k < 16; k++) s += dot4_(w4[k], hv[k]);
        s += __shfl_xor(s, 1, 64);
        s += __shfl_xor(s, 2, 64);
        s += __shfl_xor(s, 4, 64);
        if (cc == 0) grow[rl] = s;
        __syncthreads();

        u64* llcp = llc0 + (step & 1) * 4096;

        if (t < 64) {
            // parallel activations, then gather to t<16 and ONE coalesced store
            float x = pre_l + grow[t];
            float act = (lg == 2) ? tanh_f(x) : sigm_f(x);
            float ii = __shfl(act, lu, 64);
            float ff = __shfl(act, 16 + lu, 64);
            float gg = __shfl(act, 32 + lu, 64);
            float oo = __shfl(act, 48 + lu, 64);
            if (t < 16) {
                c = ff * c + ii * gg;
                float hh = oo * tanh_f(c);
                __hip_atomic_store(&llcp[wg * 16 + t], pack_(hh, step),
                                   __ATOMIC_RELAXED, SCOPE_AGENT);
            }
        } else if (t < 128) {
            // wave 1: dedicated poller. Lane ln polls its 8 units with 8
            // pipelined 8B loads per round; stages fresh h into LDS.
            const int ln = t - 64;
            const u64* base = llcp + ln * 8;
            u64 v[8];
            for (;;) {
                bool ok = true;
                #pragma unroll
                for (int k = 0; k < 8; k++) {
                    v[k] = __hip_atomic_load(&base[k], __ATOMIC_RELAXED, SCOPE_AGENT);
                    ok &= ((int)(v[k] >> 32) == step);
                }
                if (ok) break;
            }
            #pragma unroll
            for (int k = 0; k < 8; k++) {
                int u = ln * 8 + k;
                h_pad[(u >> 6) * 68 + (u & 63)] = __uint_as_float((u32)v[k]);
            }
        }
        __syncthreads();
    }
    // final h (step 128, parity 0) is in llcb plane 0
}

// ---------------------------------------------------------------------------
// K2: fused gi + 3x(gh+upd) + ans1. 64 blocks x 512 threads (R3-proven).
// ---------------------------------------------------------------------------
extern "C" __global__ __launch_bounds__(512, 1)
void mid_k(const float* __restrict__ gWih, const float* __restrict__ gWhh,
           const float* __restrict__ gbih, const float* __restrict__ gbhh,
           const float* __restrict__ aW1, const float* __restrict__ ab1,
           const u64* __restrict__ hbuf, u64* __restrict__ mem2,
           float* __restrict__ avec)
{
    const int b = blockIdx.x;
    const int t = threadIdx.x;
    const int wave = t >> 6, lane = t & 63;

    __shared__ __align__(16) float rst[3072];
    __shared__ __align__(16) float meml[1024];
    __shared__ float gil[144];
    __shared__ float ghl[48];

    for (int i = t; i < 3072; i += 512)
        rst[i] = __uint_as_float((u32)hbuf[1024 + i]);
    __syncthreads();

    for (int r = wave; r < 144; r += 8) {
        int hop = r / 48, rr = r % 48;
        int g3 = rr >> 4, jj = rr & 15;
        int grow_g = g3 * 1024 + b * 16 + jj;
        const float* wp = gWih + (size_t)grow_g * 1024;
        const float* rp = rst + hop * 1024;
        float acc = 0.f;
        #pragma unroll
        for (int cch = 0; cch < 4; cch++) {
            float4 wv = *(const float4*)(wp + cch * 256 + lane * 4);
            float4 xv = *(const float4*)(rp + cch * 256 + lane * 4);
            acc += dot4_(wv, xv);
        }
        #pragma unroll
        for (int o = 32; o > 0; o >>= 1) acc += __shfl_xor(acc, o, 64);
        if (lane == 0) gil[r] = acc + gbih[grow_g];
    }

    for (int h = 0; h < 3; h++) {
        __syncthreads();
        if (h == 0) {
            for (int i = t; i < 1024; i += 512)
                meml[i] = __uint_as_float((u32)hbuf[i]);
        } else {
            const u64* mp = mem2 + (size_t)((h - 1) & 1) * 1024;
            for (int i = t; i < 1024; i += 512) {
                u64 w;
                for (;;) {
                    w = __hip_atomic_load(&mp[i], __ATOMIC_RELAXED, SCOPE_AGENT);
                    if ((int)(w >> 32) == h) break;
                    __builtin_amdgcn_s_sleep(1);
                }
                meml[i] = __uint_as_float((u32)w);
            }
        }
        __syncthreads();
        for (int r = wave; r < 48; r += 8) {
            int g3 = r >> 4, jj = r & 15;
            int grow_g = g3 * 1024 + b * 16 + jj;
            const float* wp = gWhh + (size_t)grow_g * 1024;
            float acc = 0.f;
            #pragma unroll
            for (int cch = 0; cch < 4; cch++) {
                float4 wv = *(const float4*)(wp + cch * 256 + lane * 4);
                float4 xv = *(const float4*)(meml + cch * 256 + lane * 4);
                acc += dot4_(wv, xv);
            }
            #pragma unroll
            for (int o = 32; o > 0; o >>= 1) acc += __shfl_xor(acc, o, 64);
            if (lane == 0) ghl[r] = acc + gbhh[grow_g];
        }
        __syncthreads();
        if (t < 16) {
            int j = b * 16 + t;
            float rr_ = sigm_f(gil[h * 48 + t]      + ghl[t]);
            float zz  = sigm_f(gil[h * 48 + 16 + t] + ghl[16 + t]);
            float nn  = tanh_f(gil[h * 48 + 32 + t] + rr_ * ghl[32 + t]);
            float mnew = (1.f - zz) * nn + zz * meml[j];
            __hip_atomic_store(&mem2[(size_t)(h & 1) * 1024 + j], pack_(mnew, h + 1),
                               __ATOMIC_RELAXED, SCOPE_AGENT);
        }
    }
    __syncthreads();
    for (int i = t; i < 1024; i += 512) {
        u64 w;
        for (;;) {
            w = __hip_atomic_load(&mem2[i], __ATOMIC_RELAXED, SCOPE_AGENT);
            if ((int)(w >> 32) == 3) break;
            __builtin_amdgcn_s_sleep(1);
        }
        meml[i] = __uint_as_float((u32)w);
    }
    __syncthreads();
    {
        int row = b * 8 + wave;
        const float* wp = aW1 + (size_t)row * 1024;
        float acc = 0.f;
        #pragma unroll
        for (int cch = 0; cch < 4; cch++) {
            float4 wv = *(const float4*)(wp + cch * 256 + lane * 4);
            float4 xv = *(const float4*)(meml + cch * 256 + lane * 4);
            acc += dot4_(wv, xv);
        }
        #pragma unroll
        for (int o = 32; o > 0; o >>= 1) acc += __shfl_xor(acc, o, 64);
        if (lane == 0) avec[row] = fmaxf(acc + ab1[row], 0.f);
    }
}

// ---------------------------------------------------------------------------
// K3: logits (32000 rows) + three uniform attention outputs (exactly 1/256).
// ---------------------------------------------------------------------------
extern "C" __global__ void ans2_k(const float* __restrict__ W2, const float* __restrict__ b2,
                                  const float* __restrict__ avec, float* __restrict__ out)
{
    const int t = threadIdx.x;
    if (blockIdx.x == 0) {
        out[t]       = 1.0f / 256.0f;
        out[t + 256] = 1.0f / 256.0f;
        out[t + 512] = 1.0f / 256.0f;
    }
    const int waveId = (blockIdx.x * 256 + t) >> 6;
    const int lane = t & 63;
    const int nw = gridDim.x * 4;
    const float4* av = (const float4*)(avec + lane * 8);
    float4 a0 = av[0], a1 = av[1];
    for (int row = waveId; row < 32000; row += nw) {
        const float4* wr = (const float4*)(W2 + (size_t)row * 512 + lane * 8);
        float acc = dot4_(wr[0], a0) + dot4_(wr[1], a1);
        #pragma unroll
        for (int o = 32; o > 0; o >>= 1) acc += __shfl_xor(acc, o, 64);
        if (lane == 0) out[768 + row] = acc + b2[row];
    }
}

// ---------------------------------------------------------------------------
extern "C" void kernel_launch(void* const* d_in, const int* in_sizes, int n_in,
                              void* d_out, int out_size, void* d_ws, size_t ws_size,
                              hipStream_t stream)
{
    (void)in_sizes; (void)n_in; (void)out_size; (void)ws_size;
    const float* qWhh = (const float*)d_in[1];
    const float* qbih = (const float*)d_in[2];
    const float* qbhh = (const float*)d_in[3];
    const float* eWhh = (const float*)d_in[5];
    const float* ebih = (const float*)d_in[6];
    const float* ebhh = (const float*)d_in[7];
    const float* gWih = (const float*)d_in[10];
    const float* gWhh = (const float*)d_in[11];
    const float* gbih = (const float*)d_in[12];
    const float* gbhh = (const float*)d_in[13];
    const float* aW1  = (const float*)d_in[14];
    const float* ab1  = (const float*)d_in[15];
    const float* aW2  = (const float*)d_in[16];
    const float* ab2  = (const float*)d_in[17];
    float* out = (float*)d_out;

    char* ws = (char*)d_ws;
    u64*   llcb = (u64*)ws;                    // 2 parity x 8 dir x 512 x 8B = 64 KB
    u64*   mem2 = (u64*)(ws + 65536);          // 2 parity x 1024 x 8B = 16 KB
    float* avec = (float*)(ws + 81920);        // 512 fp32 = 2 KB

    // No memset: 0xAA poison tag never equals a valid step/hop tag.

    hipLaunchKernelGGL(lstm_k, dim3(256), dim3(512), 0, stream,
                       qWhh, qbih, qbhh, eWhh, ebih, ebhh, llcb);
    hipLaunchKernelGGL(mid_k, dim3(64), dim3(512), 0, stream,
                       gWih, gWhh, gbih, gbhh, aW1, ab1, llcb, mem2, avec);
    hipLaunchKernelGGL(ans2_k, dim3(512), dim3(256), 0, stream, aW2, ab2, avec, out);
}

// Round 8
// 468.744 us; speedup vs baseline: 1.4565x; 1.1134x over previous
//
#include <hip/hip_runtime.h>
#include <math.h>

#define SCOPE_AGENT __HIP_MEMORY_SCOPE_AGENT
typedef unsigned long long u64;
typedef unsigned int u32;

__device__ __forceinline__ float dot4_(float4 a, float4 b) {
    return a.x * b.x + a.y * b.y + a.z * b.z + a.w * b.w;
}
__device__ __forceinline__ u64 pack_(float v, int tag) {
    return ((u64)(u32)tag << 32) | (u64)__float_as_uint(v);
}
// fast transcendentals (tolerance 1.07e-2; measured absmax <=9.8e-4 R5-R7)
__device__ __forceinline__ float sigm_f(float x) {
    return __builtin_amdgcn_rcpf(1.f + __builtin_amdgcn_exp2f(-1.44269504f * x));
}
__device__ __forceinline__ float tanh_f(float x) {
    return 2.f * __builtin_amdgcn_rcpf(1.f + __builtin_amdgcn_exp2f(-2.88539008f * x)) - 1.f;
}

// ---------------------------------------------------------------------------
// K1: 8 constant-input LSTM chains, 128 steps. 256 blocks = 8 dirs x 32 WGs,
// 512 threads. Combination of the measured-best halves:
//  * PRODUCE (R7-proven): after the grow barrier, wave 0 computes all 64
//    activations in parallel (fast v_exp_f32), shfl-gathers the 4 gates per
//    unit, and t<16 issue ONE coalesced 16x8B store (full 64B sectors -> no
//    partial-line RMW; R6's scattered publish doubled WRITE_SIZE, 2x regress).
//  * CONSUME (R3-proven): every thread polls its OWN unit's tagged word with
//    a 4-deep pipelined load burst, breaking on the OLDEST match ->
//    discovery granularity ~RT/4. (R7's batch-8 all-ready poller coarsened
//    discovery to ~1.5xRT and cost +0.8us/step.)
// Tag+parity protocol unchanged (max-skew-1; 0xAA poison tag never matches
// a valid step -> no workspace init needed).
// ---------------------------------------------------------------------------
extern "C" __global__ __launch_bounds__(512, 1)
void lstm_k(const float* __restrict__ qWhh, const float* __restrict__ qbih,
            const float* __restrict__ qbhh, const float* __restrict__ eWhh,
            const float* __restrict__ ebih, const float* __restrict__ ebhh,
            u64* __restrict__ llcb)
{
    const int b  = blockIdx.x;
    const int d  = b >> 5;     // direction 0..7
    const int wg = b & 31;     // WG within direction
    const int t  = threadIdx.x;
    const int rl = t >> 3;     // local row 0..63
    const int cc = t & 7;      // column chunk (64 cols)
    const int gate = rl >> 4;  // i,f,g,o
    const int ul   = rl & 15;
    const int gu   = wg * 16 + ul;        // global unit 0..511
    const int wrow = gate * 512 + gu;     // row of Whh [2048 x 512]

    const float *Whh, *bih, *bhh;
    if (d < 2) {
        Whh = qWhh + (size_t)d * 2048 * 512;
        bih = qbih + d * 2048;
        bhh = qbhh + d * 2048;
    } else {
        Whh = eWhh + (size_t)(d - 2) * 2048 * 512;
        bih = ebih + (d - 2) * 2048;
        bhh = ebhh + (d - 2) * 2048;
    }

    // 64 weight floats/lane, pinned resident
    float4 w4[16];
    {
        const float4* wr = (const float4*)(Whh + (size_t)wrow * 512 + cc * 64);
        #pragma unroll
        for (int k = 0; k < 16; k++) w4[k] = wr[k];
    }
    #pragma unroll
    for (int k = 0; k < 16; k++)
        asm volatile("" : "+v"(w4[k].x), "+v"(w4[k].y), "+v"(w4[k].z), "+v"(w4[k].w));

    // wave 0 lane t<64 owns (gate lg = t>>4, unit lu = t&15) for activations
    const int lg = t >> 4;
    const int lu = t & 15;
    float pre_l = 0.f, c = 0.f;
    if (t < 64) pre_l = bih[lg * 512 + wg * 16 + lu] + bhh[lg * 512 + wg * 16 + lu];

    __shared__ __align__(16) float h_pad[8 * 68];
    __shared__ float grow[64];
    for (int j = t; j < 8 * 68; j += 512) h_pad[j] = 0.f;
    __syncthreads();

    u64* llc0 = llcb + d * 512;

    for (int step = 1; step <= 128; step++) {
        // all waves: partial dot (my row, my 64 cols), reduce over col group
        const float4* hv = (const float4*)(h_pad + cc * 68);
        float s = 0.f;
        #pragma unroll
        for (int k = 0; k < 16; k++) s += dot4_(w4[k], hv[k]);
        s += __shfl_xor(s, 1, 64);
        s += __shfl_xor(s, 2, 64);
        s += __shfl_xor(s, 4, 64);
        if (cc == 0) grow[rl] = s;
        __syncthreads();

        u64* llcp = llc0 + (step & 1) * 4096;

        if (t < 64) {
            // parallel activations in 64 lanes, gather, ONE coalesced store
            float x = pre_l + grow[t];
            float act = (lg == 2) ? tanh_f(x) : sigm_f(x);
            float ii = __shfl(act, lu, 64);
            float ff = __shfl(act, 16 + lu, 64);
            float gg = __shfl(act, 32 + lu, 64);
            float oo = __shfl(act, 48 + lu, 64);
            if (t < 16) {
                c = ff * c + ii * gg;
                float hh = oo * tanh_f(c);
                __hip_atomic_store(&llcp[wg * 16 + t], pack_(hh, step),
                                   __ATOMIC_RELAXED, SCOPE_AGENT);
            }
        }

        // consume: thread t polls unit t's tagged word, 4-deep pipeline,
        // break on the OLDEST matching load (discovery ~RT/4)
        u64 w;
        for (;;) {
            u64 a0 = __hip_atomic_load(&llcp[t], __ATOMIC_RELAXED, SCOPE_AGENT);
            u64 a1 = __hip_atomic_load(&llcp[t], __ATOMIC_RELAXED, SCOPE_AGENT);
            u64 a2 = __hip_atomic_load(&llcp[t], __ATOMIC_RELAXED, SCOPE_AGENT);
            u64 a3 = __hip_atomic_load(&llcp[t], __ATOMIC_RELAXED, SCOPE_AGENT);
            if ((int)(a0 >> 32) == step) { w = a0; break; }
            if ((int)(a1 >> 32) == step) { w = a1; break; }
            if ((int)(a2 >> 32) == step) { w = a2; break; }
            if ((int)(a3 >> 32) == step) { w = a3; break; }
        }
        h_pad[(t >> 6) * 68 + (t & 63)] = __uint_as_float((u32)w);
        __syncthreads();
    }
    // final h (step 128, parity 0) is in llcb plane 0
}

// ---------------------------------------------------------------------------
// K2: fused gi + 3x(gh+upd) + ans1. 64 blocks x 512 threads (R3-proven).
// ---------------------------------------------------------------------------
extern "C" __global__ __launch_bounds__(512, 1)
void mid_k(const float* __restrict__ gWih, const float* __restrict__ gWhh,
           const float* __restrict__ gbih, const float* __restrict__ gbhh,
           const float* __restrict__ aW1, const float* __restrict__ ab1,
           const u64* __restrict__ hbuf, u64* __restrict__ mem2,
           float* __restrict__ avec)
{
    const int b = blockIdx.x;
    const int t = threadIdx.x;
    const int wave = t >> 6, lane = t & 63;

    __shared__ __align__(16) float rst[3072];
    __shared__ __align__(16) float meml[1024];
    __shared__ float gil[144];
    __shared__ float ghl[48];

    for (int i = t; i < 3072; i += 512)
        rst[i] = __uint_as_float((u32)hbuf[1024 + i]);
    __syncthreads();

    for (int r = wave; r < 144; r += 8) {
        int hop = r / 48, rr = r % 48;
        int g3 = rr >> 4, jj = rr & 15;
        int grow_g = g3 * 1024 + b * 16 + jj;
        const float* wp = gWih + (size_t)grow_g * 1024;
        const float* rp = rst + hop * 1024;
        float acc = 0.f;
        #pragma unroll
        for (int cch = 0; cch < 4; cch++) {
            float4 wv = *(const float4*)(wp + cch * 256 + lane * 4);
            float4 xv = *(const float4*)(rp + cch * 256 + lane * 4);
            acc += dot4_(wv, xv);
        }
        #pragma unroll
        for (int o = 32; o > 0; o >>= 1) acc += __shfl_xor(acc, o, 64);
        if (lane == 0) gil[r] = acc + gbih[grow_g];
    }

    for (int h = 0; h < 3; h++) {
        __syncthreads();
        if (h == 0) {
            for (int i = t; i < 1024; i += 512)
                meml[i] = __uint_as_float((u32)hbuf[i]);
        } else {
            const u64* mp = mem2 + (size_t)((h - 1) & 1) * 1024;
            for (int i = t; i < 1024; i += 512) {
                u64 w;
                for (;;) {
                    w = __hip_atomic_load(&mp[i], __ATOMIC_RELAXED, SCOPE_AGENT);
                    if ((int)(w >> 32) == h) break;
                    __builtin_amdgcn_s_sleep(1);
                }
                meml[i] = __uint_as_float((u32)w);
            }
        }
        __syncthreads();
        for (int r = wave; r < 48; r += 8) {
            int g3 = r >> 4, jj = r & 15;
            int grow_g = g3 * 1024 + b * 16 + jj;
            const float* wp = gWhh + (size_t)grow_g * 1024;
            float acc = 0.f;
            #pragma unroll
            for (int cch = 0; cch < 4; cch++) {
                float4 wv = *(const float4*)(wp + cch * 256 + lane * 4);
                float4 xv = *(const float4*)(meml + cch * 256 + lane * 4);
                acc += dot4_(wv, xv);
            }
            #pragma unroll
            for (int o = 32; o > 0; o >>= 1) acc += __shfl_xor(acc, o, 64);
            if (lane == 0) ghl[r] = acc + gbhh[grow_g];
        }
        __syncthreads();
        if (t < 16) {
            int j = b * 16 + t;
            float rr_ = sigm_f(gil[h * 48 + t]      + ghl[t]);
            float zz  = sigm_f(gil[h * 48 + 16 + t] + ghl[16 + t]);
            float nn  = tanh_f(gil[h * 48 + 32 + t] + rr_ * ghl[32 + t]);
            float mnew = (1.f - zz) * nn + zz * meml[j];
            __hip_atomic_store(&mem2[(size_t)(h & 1) * 1024 + j], pack_(mnew, h + 1),
                               __ATOMIC_RELAXED, SCOPE_AGENT);
        }
    }
    __syncthreads();
    for (int i = t; i < 1024; i += 512) {
        u64 w;
        for (;;) {
            w = __hip_atomic_load(&mem2[i], __ATOMIC_RELAXED, SCOPE_AGENT);
            if ((int)(w >> 32) == 3) break;
            __builtin_amdgcn_s_sleep(1);
        }
        meml[i] = __uint_as_float((u32)w);
    }
    __syncthreads();
    {
        int row = b * 8 + wave;
        const float* wp = aW1 + (size_t)row * 1024;
        float acc = 0.f;
        #pragma unroll
        for (int cch = 0; cch < 4; cch++) {
            float4 wv = *(const float4*)(wp + cch * 256 + lane * 4);
            float4 xv = *(const float4*)(meml + cch * 256 + lane * 4);
            acc += dot4_(wv, xv);
        }
        #pragma unroll
        for (int o = 32; o > 0; o >>= 1) acc += __shfl_xor(acc, o, 64);
        if (lane == 0) avec[row] = fmaxf(acc + ab1[row], 0.f);
    }
}

// ---------------------------------------------------------------------------
// K3: logits (32000 rows) + three uniform attention outputs (exactly 1/256).
// ---------------------------------------------------------------------------
extern "C" __global__ void ans2_k(const float* __restrict__ W2, const float* __restrict__ b2,
                                  const float* __restrict__ avec, float* __restrict__ out)
{
    const int t = threadIdx.x;
    if (blockIdx.x == 0) {
        out[t]       = 1.0f / 256.0f;
        out[t + 256] = 1.0f / 256.0f;
        out[t + 512] = 1.0f / 256.0f;
    }
    const int waveId = (blockIdx.x * 256 + t) >> 6;
    const int lane = t & 63;
    const int nw = gridDim.x * 4;
    const float4* av = (const float4*)(avec + lane * 8);
    float4 a0 = av[0], a1 = av[1];
    for (int row = waveId; row < 32000; row += nw) {
        const float4* wr = (const float4*)(W2 + (size_t)row * 512 + lane * 8);
        float acc = dot4_(wr[0], a0) + dot4_(wr[1], a1);
        #pragma unroll
        for (int o = 32; o > 0; o >>= 1) acc += __shfl_xor(acc, o, 64);
        if (lane == 0) out[768 + row] = acc + b2[row];
    }
}

// ---------------------------------------------------------------------------
extern "C" void kernel_launch(void* const* d_in, const int* in_sizes, int n_in,
                              void* d_out, int out_size, void* d_ws, size_t ws_size,
                              hipStream_t stream)
{
    (void)in_sizes; (void)n_in; (void)out_size; (void)ws_size;
    const float* qWhh = (const float*)d_in[1];
    const float* qbih = (const float*)d_in[2];
    const float* qbhh = (const float*)d_in[3];
    const float* eWhh = (const float*)d_in[5];
    const float* ebih = (const float*)d_in[6];
    const float* ebhh = (const float*)d_in[7];
    const float* gWih = (const float*)d_in[10];
    const float* gWhh = (const float*)d_in[11];
    const float* gbih = (const float*)d_in[12];
    const float* gbhh = (const float*)d_in[13];
    const float* aW1  = (const float*)d_in[14];
    const float* ab1  = (const float*)d_in[15];
    const float* aW2  = (const float*)d_in[16];
    const float* ab2  = (const float*)d_in[17];
    float* out = (float*)d_out;

    char* ws = (char*)d_ws;
    u64*   llcb = (u64*)ws;                    // 2 parity x 8 dir x 512 x 8B = 64 KB
    u64*   mem2 = (u64*)(ws + 65536);          // 2 parity x 1024 x 8B = 16 KB
    float* avec = (float*)(ws + 81920);        // 512 fp32 = 2 KB

    // No memset: 0xAA poison tag never equals a valid step/hop tag.

    hipLaunchKernelGGL(lstm_k, dim3(256), dim3(512), 0, stream,
                       qWhh, qbih, qbhh, eWhh, ebih, ebhh, llcb);
    hipLaunchKernelGGL(mid_k, dim3(64), dim3(512), 0, stream,
                       gWih, gWhh, gbih, gbhh, aW1, ab1, llcb, mem2, avec);
    hipLaunchKernelGGL(ans2_k, dim3(512), dim3(256), 0, stream, aW2, ab2, avec, out);
}